// Round 1
// baseline (244.550 us; speedup 1.0000x reference)
//
#include <hip/hip_runtime.h>

// AffineLayer2d: 256 3x3 matrix exponentials -> affine grids -> bilinear sample.
// Shapes fixed by setup_inputs(): x[8,3,224,224] f32, ksamp[6,8,32] f32, rf[6] f32.
// Output [8,32,3,224,224] f32 = 154 MB  -> write-BW-bound kernel.

#define PI_F 3.14159265358979323846f

constexpr int N_ = 8, C_ = 3, H_ = 224, W_ = 224, S_ = 32;
constexpr int HW_ = H_ * W_;            // 50176
constexpr int B_ = N_ * S_;             // 256 transforms
constexpr int BLOCKS_PER_IMG = HW_ / 256; // 196 (exact)

// ---------------- Stage 1: theta = expm(M)[:, :2, :] ----------------
__global__ void theta_kernel(const float* __restrict__ ksamp,
                             const float* __restrict__ rf,
                             float* __restrict__ theta) {
    int t = threadIdx.x;
    if (t >= B_) return;
    int n = t / S_, s = t % S_;

    float kk[6];
#pragma unroll
    for (int j = 0; j < 6; ++j)
        kk[j] = ksamp[j * (N_ * S_) + n * S_ + s] * 2.f - 1.f;

    float c2 = fminf(fmaxf(rf[2], -PI_F), PI_F);
    float a = kk[0] * rf[0];   // x-translate
    float b = kk[1] * rf[1];   // y-translate
    float r = kk[2] * c2;      // rotation
    float d = kk[3] * rf[3];   // x-scale
    float e = kk[4] * rf[4];   // y-scale
    float f = kk[5] * rf[5];   // shear

    // M = d*G4 + e*G5 + r*G3 + f*G6 + a*G1 + b*G2 (third row zero)
    float A[9] = { d,     f - r, a,
                   f + r, e,     b,
                   0.f,   0.f,   0.f };

    // scaling-and-squaring, s=6, 12 Taylor terms (matches reference expm3)
#pragma unroll
    for (int i = 0; i < 9; ++i) A[i] *= (1.f / 64.f);

    float out[9] = {1,0,0, 0,1,0, 0,0,1};
#pragma unroll
    for (int i = 0; i < 9; ++i) out[i] += A[i];

    float term[9];
#pragma unroll
    for (int i = 0; i < 9; ++i) term[i] = A[i];

    for (int it = 2; it <= 12; ++it) {
        float inv = 1.f / (float)it;
        float nt[9];
#pragma unroll
        for (int rr = 0; rr < 3; ++rr)
#pragma unroll
            for (int cc = 0; cc < 3; ++cc)
                nt[rr*3+cc] = (term[rr*3+0]*A[0*3+cc] +
                               term[rr*3+1]*A[1*3+cc] +
                               term[rr*3+2]*A[2*3+cc]) * inv;
#pragma unroll
        for (int i = 0; i < 9; ++i) { term[i] = nt[i]; out[i] += nt[i]; }
    }
    for (int sq = 0; sq < 6; ++sq) {
        float nt[9];
#pragma unroll
        for (int rr = 0; rr < 3; ++rr)
#pragma unroll
            for (int cc = 0; cc < 3; ++cc)
                nt[rr*3+cc] = out[rr*3+0]*out[0*3+cc] +
                              out[rr*3+1]*out[1*3+cc] +
                              out[rr*3+2]*out[2*3+cc];
#pragma unroll
        for (int i = 0; i < 9; ++i) out[i] = nt[i];
    }

    theta[t*6+0] = out[0]; theta[t*6+1] = out[1]; theta[t*6+2] = out[2];
    theta[t*6+3] = out[3]; theta[t*6+4] = out[4]; theta[t*6+5] = out[5];
}

// ---------------- Stage 2: affine grid + bilinear sample ----------------
// One thread per (b, h, w); 3 channels per thread (shares corner idx/weights).
// blockIdx -> (b, pixel) with b wave-uniform (HW is an exact multiple of 256).
__global__ __launch_bounds__(256) void sample_kernel(const float* __restrict__ x,
                                                     const float* __restrict__ theta,
                                                     float* __restrict__ out) {
    int blk = blockIdx.x;
    int b   = blk / BLOCKS_PER_IMG;                    // uniform per block
    int pix = (blk % BLOCKS_PER_IMG) * 256 + threadIdx.x;
    int h = pix / W_, w = pix % W_;
    int n = b / S_;

    const float* th = theta + b * 6;
    float t00 = th[0], t01 = th[1], t02 = th[2];
    float t10 = th[3], t11 = th[4], t12 = th[5];

    float gx = fmaf((float)w, 2.f / (W_ - 1), -1.f);
    float gy = fmaf((float)h, 2.f / (H_ - 1), -1.f);

    float gridx = t00 * gx + t01 * gy + t02;
    float gridy = t10 * gx + t11 * gy + t12;

    float ix = (gridx + 1.f) * (0.5f * (W_ - 1));
    float iy = (gridy + 1.f) * (0.5f * (H_ - 1));

    float x0f = floorf(ix), y0f = floorf(iy);
    float wx1 = ix - x0f, wx0 = 1.f - wx1;
    float wy1 = iy - y0f, wy0 = 1.f - wy1;

    int x0 = (int)x0f, y0 = (int)y0f;
    int x1 = x0 + 1,   y1 = y0 + 1;

    bool vx0 = (x0 >= 0) && (x0 <= W_ - 1);
    bool vx1 = (x1 >= 0) && (x1 <= W_ - 1);
    bool vy0 = (y0 >= 0) && (y0 <= H_ - 1);
    bool vy1 = (y1 >= 0) && (y1 <= H_ - 1);

    float w00 = (vy0 && vx0) ? wy0 * wx0 : 0.f;
    float w01 = (vy0 && vx1) ? wy0 * wx1 : 0.f;
    float w10 = (vy1 && vx0) ? wy1 * wx0 : 0.f;
    float w11 = (vy1 && vx1) ? wy1 * wx1 : 0.f;

    int x0c = min(max(x0, 0), W_ - 1), x1c = min(max(x1, 0), W_ - 1);
    int y0c = min(max(y0, 0), H_ - 1), y1c = min(max(y1, 0), H_ - 1);

    int i00 = y0c * W_ + x0c, i01 = y0c * W_ + x1c;
    int i10 = y1c * W_ + x0c, i11 = y1c * W_ + x1c;

    const float* imgb = x + n * (C_ * HW_);
    float* ob = out + (size_t)b * (C_ * HW_) + pix;

#pragma unroll
    for (int c = 0; c < C_; ++c) {
        const float* img = imgb + c * HW_;
        float v = w00 * img[i00] + w01 * img[i01] +
                  w10 * img[i10] + w11 * img[i11];
        ob[(size_t)c * HW_] = v;
    }
}

extern "C" void kernel_launch(void* const* d_in, const int* in_sizes, int n_in,
                              void* d_out, int out_size, void* d_ws, size_t ws_size,
                              hipStream_t stream) {
    const float* x     = (const float*)d_in[0];
    const float* ksamp = (const float*)d_in[1];
    const float* rf    = (const float*)d_in[2];
    float* out   = (float*)d_out;
    float* theta = (float*)d_ws;   // 256*6 floats = 6 KB

    theta_kernel<<<1, 256, 0, stream>>>(ksamp, rf, theta);
    sample_kernel<<<B_ * BLOCKS_PER_IMG, 256, 0, stream>>>(x, theta, out);
}

// Round 2
// 179.989 us; speedup vs baseline: 1.3587x; 1.3587x over previous
//
#include <hip/hip_runtime.h>

// AffineLayer2d: 256 3x3 expm -> affine grid -> bilinear sample.
// x[8,3,224,224] f32, ksamp[6,8,32] f32, rf[6] f32 -> out[8,32,3,224,224] f32.
//
// R1 analysis: sample kernel is TA/TD (scattered-VMEM) bound, not BW bound
// (1447 GB/s = 18% peak, VALUBusy 24%, 12 scalar gathers/thread).
// R2 change: pre-reformat image to NHWC-pad4 (float4/pixel) in d_ws; sample
// does 4 aligned dwordx4 gathers (one per corner, all channels) = 3x fewer
// cacheline touches, 15->7 VMEM insts per thread.

#define PI_F 3.14159265358979323846f

constexpr int N_ = 8, C_ = 3, H_ = 224, W_ = 224, S_ = 32;
constexpr int HW_ = H_ * W_;              // 50176
constexpr int B_ = N_ * S_;               // 256 transforms
constexpr int BLOCKS_PER_IMG = HW_ / 256; // 196 (exact)

// ws layout: [0, 6144)   theta (256 * 6 floats)
//            [8192, ...) xi    (N*HW float4 = 25.7 MB), 16B-aligned
constexpr size_t THETA_OFF = 0;
constexpr size_t XI_OFF    = 8192;

// ---------------- Stage 1: reformat NCHW->NHWC(pad4) + theta ----------------
__device__ void compute_theta(const float* __restrict__ ksamp,
                              const float* __restrict__ rf,
                              float* __restrict__ theta) {
    int t = threadIdx.x;  // 256 threads = 256 transforms
    int n = t / S_, s = t % S_;

    float kk[6];
#pragma unroll
    for (int j = 0; j < 6; ++j)
        kk[j] = ksamp[j * (N_ * S_) + n * S_ + s] * 2.f - 1.f;

    float c2 = fminf(fmaxf(rf[2], -PI_F), PI_F);
    float a = kk[0] * rf[0];
    float b = kk[1] * rf[1];
    float r = kk[2] * c2;
    float d = kk[3] * rf[3];
    float e = kk[4] * rf[4];
    float f = kk[5] * rf[5];

    float A[9] = { d,     f - r, a,
                   f + r, e,     b,
                   0.f,   0.f,   0.f };

#pragma unroll
    for (int i = 0; i < 9; ++i) A[i] *= (1.f / 64.f);

    float out[9] = {1,0,0, 0,1,0, 0,0,1};
#pragma unroll
    for (int i = 0; i < 9; ++i) out[i] += A[i];

    float term[9];
#pragma unroll
    for (int i = 0; i < 9; ++i) term[i] = A[i];

#pragma unroll
    for (int it = 2; it <= 12; ++it) {
        float inv = 1.f / (float)it;
        float nt[9];
#pragma unroll
        for (int rr = 0; rr < 3; ++rr)
#pragma unroll
            for (int cc = 0; cc < 3; ++cc)
                nt[rr*3+cc] = (term[rr*3+0]*A[0*3+cc] +
                               term[rr*3+1]*A[1*3+cc] +
                               term[rr*3+2]*A[2*3+cc]) * inv;
#pragma unroll
        for (int i = 0; i < 9; ++i) { term[i] = nt[i]; out[i] += nt[i]; }
    }
#pragma unroll
    for (int sq = 0; sq < 6; ++sq) {
        float nt[9];
#pragma unroll
        for (int rr = 0; rr < 3; ++rr)
#pragma unroll
            for (int cc = 0; cc < 3; ++cc)
                nt[rr*3+cc] = out[rr*3+0]*out[0*3+cc] +
                              out[rr*3+1]*out[1*3+cc] +
                              out[rr*3+2]*out[2*3+cc];
#pragma unroll
        for (int i = 0; i < 9; ++i) out[i] = nt[i];
    }

    theta[t*6+0] = out[0]; theta[t*6+1] = out[1]; theta[t*6+2] = out[2];
    theta[t*6+3] = out[3]; theta[t*6+4] = out[4]; theta[t*6+5] = out[5];
}

__global__ __launch_bounds__(256) void prep_kernel(const float* __restrict__ x,
                                                   const float* __restrict__ ksamp,
                                                   const float* __restrict__ rf,
                                                   float4* __restrict__ xi,
                                                   float* __restrict__ theta) {
    int idx = blockIdx.x * 256 + threadIdx.x;   // over N*HW
    int n = idx / HW_, p = idx - n * HW_;
    const float* base = x + n * (C_ * HW_) + p;
    float4 v;
    v.x = base[0];
    v.y = base[HW_];
    v.z = base[2 * HW_];
    v.w = 0.f;
    xi[idx] = v;

    if (blockIdx.x == 0) compute_theta(ksamp, rf, theta);
}

// ---------------- Stage 2: affine grid + bilinear sample ----------------
__global__ __launch_bounds__(256) void sample_kernel(const float4* __restrict__ xi,
                                                     const float* __restrict__ theta,
                                                     float* __restrict__ out) {
    int blk = blockIdx.x;
    int b   = blk / BLOCKS_PER_IMG;                    // uniform per block
    int pix = (blk % BLOCKS_PER_IMG) * 256 + threadIdx.x;
    int h = pix / W_, w = pix - h * W_;
    int n = b / S_;

    const float* th = theta + b * 6;
    float t00 = th[0], t01 = th[1], t02 = th[2];
    float t10 = th[3], t11 = th[4], t12 = th[5];

    float gx = fmaf((float)w, 2.f / (W_ - 1), -1.f);
    float gy = fmaf((float)h, 2.f / (H_ - 1), -1.f);

    float gridx = t00 * gx + t01 * gy + t02;
    float gridy = t10 * gx + t11 * gy + t12;

    float ix = (gridx + 1.f) * (0.5f * (W_ - 1));
    float iy = (gridy + 1.f) * (0.5f * (H_ - 1));

    float x0f = floorf(ix), y0f = floorf(iy);
    float wx1 = ix - x0f, wx0 = 1.f - wx1;
    float wy1 = iy - y0f, wy0 = 1.f - wy1;

    int x0 = (int)x0f, y0 = (int)y0f;
    int x1 = x0 + 1,   y1 = y0 + 1;

    bool vx0 = (x0 >= 0) && (x0 <= W_ - 1);
    bool vx1 = (x1 >= 0) && (x1 <= W_ - 1);
    bool vy0 = (y0 >= 0) && (y0 <= H_ - 1);
    bool vy1 = (y1 >= 0) && (y1 <= H_ - 1);

    float w00 = (vy0 && vx0) ? wy0 * wx0 : 0.f;
    float w01 = (vy0 && vx1) ? wy0 * wx1 : 0.f;
    float w10 = (vy1 && vx0) ? wy1 * wx0 : 0.f;
    float w11 = (vy1 && vx1) ? wy1 * wx1 : 0.f;

    int x0c = min(max(x0, 0), W_ - 1), x1c = min(max(x1, 0), W_ - 1);
    int y0c = min(max(y0, 0), H_ - 1), y1c = min(max(y1, 0), H_ - 1);

    const float4* img = xi + n * HW_;
    float4 p00 = img[y0c * W_ + x0c];
    float4 p01 = img[y0c * W_ + x1c];
    float4 p10 = img[y1c * W_ + x0c];
    float4 p11 = img[y1c * W_ + x1c];

    float vx = w00 * p00.x + w01 * p01.x + w10 * p10.x + w11 * p11.x;
    float vy = w00 * p00.y + w01 * p01.y + w10 * p10.y + w11 * p11.y;
    float vz = w00 * p00.z + w01 * p01.z + w10 * p10.z + w11 * p11.z;

    float* ob = out + (size_t)b * (C_ * HW_) + pix;
    ob[0]            = vx;
    ob[HW_]          = vy;
    ob[2 * (size_t)HW_] = vz;
}

extern "C" void kernel_launch(void* const* d_in, const int* in_sizes, int n_in,
                              void* d_out, int out_size, void* d_ws, size_t ws_size,
                              hipStream_t stream) {
    const float* x     = (const float*)d_in[0];
    const float* ksamp = (const float*)d_in[1];
    const float* rf    = (const float*)d_in[2];
    float* out   = (float*)d_out;
    float* theta = (float*)((char*)d_ws + THETA_OFF);
    float4* xi   = (float4*)((char*)d_ws + XI_OFF);

    prep_kernel<<<N_ * BLOCKS_PER_IMG, 256, 0, stream>>>(x, ksamp, rf, xi, theta);
    sample_kernel<<<B_ * BLOCKS_PER_IMG, 256, 0, stream>>>(xi, theta, out);
}